// Round 1
// baseline (634.180 us; speedup 1.0000x reference)
//
#include <hip/hip_runtime.h>
#include <hip/hip_bf16.h>

typedef __attribute__((ext_vector_type(8))) short short8;
typedef __attribute__((ext_vector_type(4))) short short4_t;
typedef __attribute__((ext_vector_type(4))) float floatx4;

#define MFMA_B16(a,b,c) __builtin_amdgcn_mfma_f32_16x16x32_bf16((a),(b),(c),0,0,0)

__device__ __forceinline__ short f2bf(float f) {
    union { __hip_bfloat16 h; short s; } u;
    u.h = __float2bfloat16(f);
    return u.s;
}

// ---------------- problem constants ----------------
#define N_FRAMES 4096
#define C_IN     9
#define IMG_HW   11
#define POS      121      // 11*11
#define PADW     13
#define PADPOS   169      // 13*13
#define NF       64
#define ASTR     72       // act LDS stride per padded position (elems); 144B = 16B-aligned, 2-way banks only
#define FC_K     7744     // 121*64

// ---------------- workspace offsets (bytes) ----------------
#define OFF_W0    0                       // [9][64][16] bf16 conv0 weights packed  (18432 B)
#define OFF_WP    18432                   // [7][9][64][64] bf16 conv weights packed (516096 B)
#define OFF_FCP   534528                  // [64][7744] bf16 fc weights permuted (k = p*64+c) (991232 B)
#define OFF_WIHT  1525760                 // [64][256] f32 w_ih^T (65536 B)
#define OFF_BSUM  1591296                 // [256] f32 b_ih+b_hh (1024 B)
#define OFF_ACTS  1592320                 // [4096][7744] bf16 final conv acts (63438848 B)
#define OFF_FEATS 65031168                // [4096][64] f32 (1048576 B)
#define OFF_XG    66079744                // [4096][256] f32 (4194304 B)
#define OFF_HOUT  70274048                // [4096][64] f32 (1048576 B)

// ================= prep: pack/permute weights =================
__global__ __launch_bounds__(256) void prep_kernel(
    const float* __restrict__ conv0_w, const float* __restrict__ conv_ws,
    const float* __restrict__ fc_w, const float* __restrict__ w_ih,
    const float* __restrict__ b_ih, const float* __restrict__ b_hh,
    short* __restrict__ w0, short* __restrict__ wpk, short* __restrict__ fcp,
    float* __restrict__ wihT, float* __restrict__ bsum)
{
    int idx = blockIdx.x*256 + threadIdx.x;
    if (idx < 9216) {  // conv0: [o9][o][ci16], ci>=9 zero. conv0_w is [64][9][3][3]
        int o9 = idx >> 10; int r = idx & 1023; int o = r >> 4; int ci = r & 15;
        float v = (ci < 9) ? conv0_w[(o*9 + ci)*9 + o9] : 0.f;
        w0[idx] = f2bf(v);
        return;
    }
    idx -= 9216;
    if (idx < 258048) {  // conv1-7: [l][o9][o][ci]. conv_ws is [7][64][64][3][3]
        int l = idx / 36864; int r = idx % 36864; int o9 = r >> 12; int rr = r & 4095;
        int o = rr >> 6; int ci = rr & 63;
        wpk[idx] = f2bf(conv_ws[((l*64 + o)*64 + ci)*9 + o9]);
        return;
    }
    idx -= 258048;
    if (idx < 495616) {  // fc: [u][k_new], k_new = p*64+c, ref k = c*121+p
        int u = idx / FC_K; int k = idx % FC_K; int p = k >> 6; int c = k & 63;
        fcp[idx] = f2bf(fc_w[u*FC_K + c*121 + p]);
        return;
    }
    idx -= 495616;
    if (idx < 16384) {  // w_ih^T: [k][g]
        int k = idx >> 8; int g = idx & 255;
        wihT[idx] = w_ih[g*64 + k];
        return;
    }
    idx -= 16384;
    if (idx < 256) bsum[idx] = b_ih[idx] + b_hh[idx];
}

// ================= fused 8-layer conv stack, one wave per frame =================
__global__ __launch_bounds__(64) void conv_stack(
    const float* __restrict__ x,
    const float* __restrict__ conv0_b,
    const float* __restrict__ conv_bs,
    const short* __restrict__ w0,
    const short* __restrict__ wpk,
    short* __restrict__ acts_out)
{
    __shared__ alignas(16) short act[PADPOS*ASTR];   // 24336 B, padded 13x13x(64 in stride-72 runs)
    __shared__ alignas(16) short in0[PADPOS*16];     // 5408 B, conv0 input, ci padded 9->16

    const int f    = blockIdx.x;
    const int lane = threadIdx.x;
    const int m    = lane & 15;
    const int kg   = lane >> 4;

    const short8 zero8 = {0,0,0,0,0,0,0,0};
    const floatx4 fzero = {0.f,0.f,0.f,0.f};

    for (int i = lane*8; i < PADPOS*ASTR; i += 64*8) *(short8*)(&act[i]) = zero8;
    for (int i = lane*8; i < PADPOS*16;   i += 64*8) *(short8*)(&in0[i]) = zero8;
    __syncthreads();

    // stage input frame fp32 -> bf16 into padded in0 ([y][x][ci], x is [ci][y][x])
    const float* xf = x + f*(C_IN*POS);
    for (int i = lane; i < C_IN*POS; i += 64) {
        int ci = i / POS;
        int p  = i - ci*POS;
        int yy = p / IMG_HW;
        int xx = p - yy*IMG_HW;
        in0[((yy+1)*PADW + (xx+1))*16 + ci] = f2bf(xf[i]);
    }
    __syncthreads();

    // per-lane fragment base addresses
    int vb[8], vb0[8], vs[8];
    bool smask[8];
    #pragma unroll
    for (int nt = 0; nt < 8; ++nt) {
        int p = nt*16 + m;
        smask[nt] = (p <= 120);
        int pc = smask[nt] ? p : 120;
        int yy = pc / IMG_HW;
        int xx = pc - yy*IMG_HW;
        vb[nt]  = (yy*PADW + xx)*ASTR + kg*8;
        vb0[nt] = (yy*PADW + xx)*16 + (kg & 1)*8;
        vs[nt]  = ((yy+1)*PADW + (xx+1))*ASTR;
    }

    floatx4 acc[4][8];
    #pragma unroll
    for (int mt=0;mt<4;mt++)
        #pragma unroll
        for (int nt=0;nt<8;nt++) acc[mt][nt] = fzero;

    const bool kzero = (kg >= 2);   // conv0: K padded 16->32, upper half zero

    // ---- conv0 (K=16 real, via zero-padded K=32) ----
    {
        int aoff[4];
        #pragma unroll
        for (int mt=0;mt<4;mt++) aoff[mt] = (mt*16 + m)*16 + (kg&1)*8;
        #pragma unroll
        for (int o9 = 0; o9 < 9; ++o9) {
            const int sb = ((o9/3)*PADW + (o9%3))*16;
            short8 a[4], b[8];
            #pragma unroll
            for (int mt=0;mt<4;mt++) {
                a[mt] = *(const short8*)(w0 + o9*1024 + aoff[mt]);
                if (kzero) a[mt] = zero8;
            }
            #pragma unroll
            for (int nt=0;nt<8;nt++) {
                b[nt] = *(const short8*)(&in0[vb0[nt] + sb]);
                if (kzero) b[nt] = zero8;
            }
            #pragma unroll
            for (int mt=0;mt<4;mt++)
                #pragma unroll
                for (int nt=0;nt<8;nt++)
                    acc[mt][nt] = MFMA_B16(a[mt], b[nt], acc[mt][nt]);
        }
    }

    // epilogue: bias + relu + bf16, write back in place (wave-private frame)
    auto epilogue = [&](const float* bias) {
        __syncthreads();
        #pragma unroll
        for (int mt=0;mt<4;mt++) {
            const int m0 = mt*16 + kg*4;
            floatx4 bb = *(const floatx4*)(bias + m0);
            #pragma unroll
            for (int nt=0;nt<8;nt++) {
                floatx4 v = acc[mt][nt];
                acc[mt][nt] = fzero;
                if (!smask[nt]) continue;
                short4_t sv;
                sv.x = f2bf(fmaxf(v.x + bb.x, 0.f));
                sv.y = f2bf(fmaxf(v.y + bb.y, 0.f));
                sv.z = f2bf(fmaxf(v.z + bb.z, 0.f));
                sv.w = f2bf(fmaxf(v.w + bb.w, 0.f));
                *(short4_t*)(&act[vs[nt] + m0]) = sv;
            }
        }
        __syncthreads();
    };

    epilogue(conv0_b);

    // ---- conv layers 1..7, K=64 (2 chunks of 32), A-frags streamed from L2 ----
    int awoff[4];
    #pragma unroll
    for (int mt=0;mt<4;mt++) awoff[mt] = (mt*16 + m)*64 + kg*8;

    for (int l = 1; l < 8; ++l) {
        const short* wl = wpk + (l-1)*(9*4096);
        #pragma unroll
        for (int o9 = 0; o9 < 9; ++o9) {
            const int sb = ((o9/3)*PADW + (o9%3))*ASTR;
            #pragma unroll
            for (int kc = 0; kc < 2; ++kc) {
                short8 a[4], b[8];
                #pragma unroll
                for (int mt=0;mt<4;mt++)
                    a[mt] = *(const short8*)(wl + o9*4096 + kc*32 + awoff[mt]);
                #pragma unroll
                for (int nt=0;nt<8;nt++)
                    b[nt] = *(const short8*)(&act[vb[nt] + sb + kc*32]);
                #pragma unroll
                for (int mt=0;mt<4;mt++)
                    #pragma unroll
                    for (int nt=0;nt<8;nt++)
                        acc[mt][nt] = MFMA_B16(a[mt], b[nt], acc[mt][nt]);
            }
        }
        epilogue(conv_bs + (l-1)*NF);
    }

    // coalesced copy of final act interior -> global [f][7744], k = p*64 + c
    for (int it = 0; it < 16; ++it) {
        int q = lane + it*64;
        if (q < 968) {  // 968 chunks of 8 bf16
            int p  = q >> 3;
            int co = (q & 7)*8;
            int yy = p / IMG_HW;
            int xx = p - yy*IMG_HW;
            short8 v = *(const short8*)(&act[((yy+1)*PADW + (xx+1))*ASTR + co]);
            *(short8*)(acts_out + f*FC_K + q*8) = v;
        }
    }
}

// ================= FC GEMM: feats[4096][64] = relu(acts @ fcp^T + b) =================
__global__ __launch_bounds__(256) void fc_kernel(
    const short* __restrict__ acts, const short* __restrict__ fcp,
    const float* __restrict__ fc_b, float* __restrict__ feats)
{
    __shared__ alignas(16) float red[3*64*16];
    const int tid  = threadIdx.x;
    const int lane = tid & 63;
    const int w    = tid >> 6;
    const int m    = lane & 15;
    const int kg   = lane >> 4;
    const int bm   = blockIdx.x;     // 256 blocks x 16 frames

    const floatx4 fzero = {0.f,0.f,0.f,0.f};
    floatx4 acc[4];
    #pragma unroll
    for (int nt=0;nt<4;nt++) acc[nt] = fzero;

    const short* arow = acts + (bm*16 + m)*FC_K + kg*8;
    const short* brow = fcp + m*FC_K + kg*8;

    for (int kc = w; kc < 242; kc += 4) {   // K split across 4 waves
        short8 a = *(const short8*)(arow + kc*32);
        #pragma unroll
        for (int nt=0;nt<4;nt++) {
            short8 b = *(const short8*)(brow + nt*16*FC_K + kc*32);
            acc[nt] = MFMA_B16(a, b, acc[nt]);
        }
    }

    if (w > 0) {
        #pragma unroll
        for (int nt=0;nt<4;nt++)
            *(floatx4*)(&red[((w-1)*64 + lane)*16 + nt*4]) = acc[nt];
    }
    __syncthreads();
    if (w == 0) {
        #pragma unroll
        for (int nt=0;nt<4;nt++)
            for (int j=0;j<3;j++)
                acc[nt] += *(const floatx4*)(&red[(j*64 + lane)*16 + nt*4]);
        #pragma unroll
        for (int nt=0;nt<4;nt++) {
            int unit = nt*16 + m;                 // C col = lane&15
            float bias = fc_b[unit];
            int fr = bm*16 + kg*4;                // C row = (lane>>4)*4 + reg
            feats[(fr+0)*NF + unit] = fmaxf(acc[nt].x + bias, 0.f);
            feats[(fr+1)*NF + unit] = fmaxf(acc[nt].y + bias, 0.f);
            feats[(fr+2)*NF + unit] = fmaxf(acc[nt].z + bias, 0.f);
            feats[(fr+3)*NF + unit] = fmaxf(acc[nt].w + bias, 0.f);
        }
    }
}

// ================= xg = feats @ w_ih^T + b_ih + b_hh (fp32) =================
__global__ __launch_bounds__(256) void xg_kernel(
    const float* __restrict__ feats, const float* __restrict__ wihT,
    const float* __restrict__ bsum, float* __restrict__ xg)
{
    __shared__ alignas(16) float fbuf[16*64];
    const int g  = threadIdx.x;          // gate 0..255
    const int b0 = blockIdx.x * 16;      // 16 frames per block
    for (int i = g; i < 16*64; i += 256) fbuf[i] = feats[b0*64 + i];
    float wreg[64];
    #pragma unroll
    for (int k=0;k<64;k++) wreg[k] = wihT[k*256 + g];
    float bs = bsum[g];
    __syncthreads();
    for (int i=0;i<16;i++) {
        float a = bs;
        #pragma unroll
        for (int k=0;k<64;k++) a += fbuf[i*64+k]*wreg[k];
        xg[(b0+i)*256 + g] = a;
    }
}

// ================= LSTM recurrence, one block per batch element =================
__device__ __forceinline__ float sigmf_(float v){ return 1.f/(1.f + __expf(-v)); }

__global__ __launch_bounds__(128) void lstm_kernel(
    const float* __restrict__ xg, const float* __restrict__ whh,
    float* __restrict__ hout)
{
    __shared__ alignas(16) float hbuf[64];
    __shared__ alignas(16) float gbuf[256];
    const int t = threadIdx.x;           // handles gates t and t+128
    const int b = blockIdx.x;

    float4 w0v[16], w1v[16];
    #pragma unroll
    for (int k=0;k<16;k++) w0v[k] = *(const float4*)(whh + t*64 + k*4);
    #pragma unroll
    for (int k=0;k<16;k++) w1v[k] = *(const float4*)(whh + (t+128)*64 + k*4);

    float c = 0.f;
    if (t < 64) hbuf[t] = 0.f;
    __syncthreads();

    for (int ts=0; ts<128; ++ts) {
        const float* xr = xg + (b*128 + ts)*256;
        float aA = xr[t];
        float aB = xr[t+128];
        #pragma unroll
        for (int k=0;k<16;k++) {
            float4 hv = *(const float4*)(&hbuf[k*4]);
            aA += hv.x*w0v[k].x + hv.y*w0v[k].y + hv.z*w0v[k].z + hv.w*w0v[k].w;
            aB += hv.x*w1v[k].x + hv.y*w1v[k].y + hv.z*w1v[k].z + hv.w*w1v[k].w;
        }
        gbuf[t] = aA;
        gbuf[t+128] = aB;
        __syncthreads();
        if (t < 64) {   // PyTorch gate order i,f,g,o
            float ig = sigmf_(gbuf[t]);
            float fg = sigmf_(gbuf[64+t]);
            float gg = tanhf(gbuf[128+t]);
            float og = sigmf_(gbuf[192+t]);
            c = fg*c + ig*gg;
            float h = og*tanhf(c);
            hbuf[t] = h;
            hout[(b*128+ts)*64 + t] = h;
        }
        __syncthreads();
    }
}

// ================= policy/value heads (fp32) =================
__global__ __launch_bounds__(64) void heads_kernel(
    const float* __restrict__ hout,
    const float* __restrict__ p1w, const float* __restrict__ p1b,
    const float* __restrict__ p2w, const float* __restrict__ p2b,
    const float* __restrict__ v1w, const float* __restrict__ v1b,
    const float* __restrict__ v2w, const float* __restrict__ v2b,
    float* __restrict__ out)
{
    __shared__ alignas(16) float hbuf[64];
    __shared__ alignas(16) float a1[128];
    __shared__ alignas(16) float a2[128];
    const int lane = threadIdx.x;
    for (int fi=0; fi<4; ++fi) {
        const int f = blockIdx.x*4 + fi;
        hbuf[lane] = hout[f*64 + lane];
        __syncthreads();
        #pragma unroll
        for (int uu=0; uu<2; ++uu) {
            const int u = lane + uu*64;
            float s1 = p1b[u], s2 = v1b[u];
            const float4* wp1 = (const float4*)(p1w + u*64);
            const float4* wv1 = (const float4*)(v1w + u*64);
            #pragma unroll
            for (int k=0;k<16;k++) {
                float4 h4 = *(const float4*)(&hbuf[k*4]);
                float4 w4 = wp1[k];
                s1 += h4.x*w4.x + h4.y*w4.y + h4.z*w4.z + h4.w*w4.w;
                float4 q4 = wv1[k];
                s2 += h4.x*q4.x + h4.y*q4.y + h4.z*q4.z + h4.w*q4.w;
            }
            a1[u] = fmaxf(s1, 0.f);
            a2[u] = fmaxf(s2, 0.f);
        }
        __syncthreads();
        if (lane < 6) {
            float s = p2b[lane];
            const float* wr = p2w + lane*128;
            #pragma unroll
            for (int j=0;j<128;j++) s += a1[j]*wr[j];
            out[f*6 + lane] = s;
        }
        if (lane == 6) {
            float s = v2b[0];
            #pragma unroll
            for (int j=0;j<128;j++) s += a2[j]*v2w[j];
            out[24576 + f] = s;   // v after p (24576 = 4096*6)
        }
        __syncthreads();
    }
}

extern "C" void kernel_launch(void* const* d_in, const int* in_sizes, int n_in,
                              void* d_out, int out_size, void* d_ws, size_t ws_size,
                              hipStream_t stream) {
    const float* x       = (const float*)d_in[0];
    const float* conv0_w = (const float*)d_in[1];
    const float* conv0_b = (const float*)d_in[2];
    const float* conv_ws = (const float*)d_in[3];
    const float* conv_bs = (const float*)d_in[4];
    const float* fc_w    = (const float*)d_in[5];
    const float* fc_b    = (const float*)d_in[6];
    const float* w_ih    = (const float*)d_in[7];
    const float* w_hh    = (const float*)d_in[8];
    const float* b_ih    = (const float*)d_in[9];
    const float* b_hh    = (const float*)d_in[10];
    const float* p1_w    = (const float*)d_in[11];
    const float* p1_b    = (const float*)d_in[12];
    const float* p2_w    = (const float*)d_in[13];
    const float* p2_b    = (const float*)d_in[14];
    const float* v1_w    = (const float*)d_in[15];
    const float* v1_b    = (const float*)d_in[16];
    const float* v2_w    = (const float*)d_in[17];
    const float* v2_b    = (const float*)d_in[18];
    float* out = (float*)d_out;

    char* ws = (char*)d_ws;
    short* w0    = (short*)(ws + OFF_W0);
    short* wpk   = (short*)(ws + OFF_WP);
    short* fcp   = (short*)(ws + OFF_FCP);
    float* wihT  = (float*)(ws + OFF_WIHT);
    float* bsum  = (float*)(ws + OFF_BSUM);
    short* acts  = (short*)(ws + OFF_ACTS);
    float* feats = (float*)(ws + OFF_FEATS);
    float* xgb   = (float*)(ws + OFF_XG);
    float* hout  = (float*)(ws + OFF_HOUT);

    prep_kernel<<<3045, 256, 0, stream>>>(conv0_w, conv_ws, fc_w, w_ih, b_ih, b_hh,
                                          w0, wpk, fcp, wihT, bsum);
    conv_stack<<<N_FRAMES, 64, 0, stream>>>(x, conv0_b, conv_bs, w0, wpk, acts);
    fc_kernel<<<256, 256, 0, stream>>>(acts, fcp, fc_b, feats);
    xg_kernel<<<256, 256, 0, stream>>>(feats, wihT, bsum, xgb);
    lstm_kernel<<<32, 128, 0, stream>>>(xgb, w_hh, hout);
    heads_kernel<<<1024, 64, 0, stream>>>(hout, p1_w, p1_b, p2_w, p2_b,
                                          v1_w, v1_b, v2_w, v2_b, out);
}